// Round 5
// baseline (1397.305 us; speedup 1.0000x reference)
//
#include <hip/hip_runtime.h>
#include <hip/hip_bf16.h>

#define BATCH   16384
#define NIN     784
#define NH      384
#define NLAYERS 6
#define NOUT    10
#define EPS_BN  1e-5f
#define LOSCALE 2048.0f
#define LOINV   (1.0f/2048.0f)
#define NPART   64
#define PSTRIDE 1024

typedef __attribute__((ext_vector_type(8))) _Float16 f16x8;
typedef __attribute__((ext_vector_type(4))) _Float16 f16x4;
typedef __attribute__((ext_vector_type(4))) float f32x4;

// ---------------------------------------------------------------------------
// Column stats (two-stage, deterministic).  src [B, C] f32 row-major.
__global__ __launch_bounds__(256) void stats_partial(
        const float* __restrict__ src, int C, int applyRelu,
        float* __restrict__ psum, float* __restrict__ psq) {
    int c = blockIdx.x * 256 + threadIdx.x;
    if (c >= C) return;
    int r0 = blockIdx.y * (BATCH / NPART);
    float s = 0.f, q = 0.f;
    for (int r = r0; r < r0 + BATCH / NPART; ++r) {
        float v = src[(size_t)r * C + c];
        if (applyRelu) v = fmaxf(v, 0.f);
        s += v; q += v * v;
    }
    psum[blockIdx.y * PSTRIDE + c] = s;
    psq [blockIdx.y * PSTRIDE + c] = q;
}

__global__ __launch_bounds__(256) void stats_finalize(
        const float* __restrict__ psum, const float* __restrict__ psq, int C,
        const float* __restrict__ gamma, const float* __restrict__ beta,
        float* __restrict__ a_out, float* __restrict__ c_out) {
    int c = blockIdx.x * 256 + threadIdx.x;
    if (c >= C) return;
    float s = 0.f, q = 0.f;
    for (int i = 0; i < NPART; ++i) { s += psum[i * PSTRIDE + c]; q += psq[i * PSTRIDE + c]; }
    const float invB = 1.f / (float)BATCH;
    float mu  = s * invB;
    float var = q * invB - mu * mu;
    float rs  = rsqrtf(var + EPS_BN);
    float g   = gamma[c];
    a_out[c] = g * rs;
    c_out[c] = beta[c] - g * mu * rs;
}

// ---------------------------------------------------------------------------
// Wp[j][n] = a[n]*W_in[j][n] split into f16 hi/lo(scaled).  4 elems/thread.
__global__ __launch_bounds__(256) void scale_win_hl(
        const float* __restrict__ W_in, const float* __restrict__ a,
        _Float16* __restrict__ whi, _Float16* __restrict__ wlo) {
    int i = blockIdx.x * 256 + threadIdx.x;
    if (i >= NH * NIN / 4) return;
    int n = (i * 4) % NIN;
    float4 wv = ((const float4*)W_in)[i];
    float v[4] = { wv.x * a[n], wv.y * a[n + 1], wv.z * a[n + 2], wv.w * a[n + 3] };
    f16x4 h4, l4;
    #pragma unroll
    for (int j = 0; j < 4; ++j) {
        _Float16 h = (_Float16)v[j];
        h4[j] = h;
        l4[j] = (_Float16)((v[j] - (float)h) * LOSCALE);
    }
    *(f16x4*)(whi + (size_t)i * 4) = h4;
    *(f16x4*)(wlo + (size_t)i * 4) = l4;
}

// f32 -> f16 hi/lo(scaled) split, 4 elems/thread (for Wd chunks)
__global__ __launch_bounds__(256) void conv_hl(
        const float* __restrict__ src, _Float16* __restrict__ hi,
        _Float16* __restrict__ lo, int n4) {
    int i = blockIdx.x * 256 + threadIdx.x;
    if (i >= n4) return;
    float4 wv = ((const float4*)src)[i];
    float v[4] = { wv.x, wv.y, wv.z, wv.w };
    f16x4 h4, l4;
    #pragma unroll
    for (int j = 0; j < 4; ++j) {
        _Float16 h = (_Float16)v[j];
        h4[j] = h;
        l4[j] = (_Float16)((v[j] - (float)h) * LOSCALE);
    }
    *(f16x4*)(hi + (size_t)i * 4) = h4;
    *(f16x4*)(lo + (size_t)i * 4) = l4;
}

// b'[j] = b_in[j] + sum_n c[n]*W_in[j,n]  (f32, exact)
__global__ __launch_bounds__(64) void bias_in(
        const float* __restrict__ W_in, const float* __restrict__ b_in,
        const float* __restrict__ cvec, float* __restrict__ bp) {
    int j = blockIdx.x;
    int lane = threadIdx.x;
    float s = 0.f;
    for (int n = lane; n < NIN; n += 64) s += cvec[n] * W_in[j * NIN + n];
    #pragma unroll
    for (int m = 1; m < 64; m <<= 1) s += __shfl_xor(s, m, 64);
    if (lane == 0) bp[j] = b_in[j] + s;
}

// ---------------------------------------------------------------------------
// Input GEMM (fp16x3 MFMA): pre[b,j] = X[b,:].Wp[j,:] + bp[j]
// grid (256, 4), block 256. Wave: 16 batch rows x 96 n-cols (ct=6).
__global__ __launch_bounds__(256, 4) void gemm_in_mfma(
        const float* __restrict__ X, const _Float16* __restrict__ Wphi,
        const _Float16* __restrict__ Wplo, const float* __restrict__ bp,
        float* __restrict__ pre) {
    int tid = threadIdx.x;
    int w = tid >> 6, l = tid & 63, lr = l & 15, lq = l >> 4;
    int b0 = blockIdx.x * 64;
    int n0 = blockIdx.y * 96;
    const float* xrow = X + (size_t)(b0 + w * 16 + lr) * NIN;
    f32x4 acc[6], acr[6];
    #pragma unroll
    for (int ct = 0; ct < 6; ++ct)
        #pragma unroll
        for (int r = 0; r < 4; ++r) { acc[ct][r] = 0.f; acr[ct][r] = 0.f; }
    for (int kc = 0; kc < 24; ++kc) {
        int k0 = kc * 32 + lq * 8;
        float4 x0 = *(const float4*)(xrow + k0);
        float4 x1 = *(const float4*)(xrow + k0 + 4);
        float xv[8] = { x0.x, x0.y, x0.z, x0.w, x1.x, x1.y, x1.z, x1.w };
        f16x8 ahi, alo;
        #pragma unroll
        for (int j = 0; j < 8; ++j) {
            _Float16 h = (_Float16)xv[j];
            ahi[j] = h;
            alo[j] = (_Float16)((xv[j] - (float)h) * LOSCALE);
        }
        #pragma unroll
        for (int ct = 0; ct < 6; ++ct) {
            size_t off = (size_t)(n0 + ct * 16 + lr) * NIN + k0;
            f16x8 bhi = *(const f16x8*)(Wphi + off);
            f16x8 blo = *(const f16x8*)(Wplo + off);
            acc[ct] = __builtin_amdgcn_mfma_f32_16x16x32_f16(ahi, bhi, acc[ct], 0, 0, 0);
            acr[ct] = __builtin_amdgcn_mfma_f32_16x16x32_f16(ahi, blo, acr[ct], 0, 0, 0);
            acr[ct] = __builtin_amdgcn_mfma_f32_16x16x32_f16(alo, bhi, acr[ct], 0, 0, 0);
        }
    }
    {   // K tail 768..783 (16 valid): lanes lq>=2 contribute zeros
        f16x8 ahi, alo;
        #pragma unroll
        for (int j = 0; j < 8; ++j) { ahi[j] = (_Float16)0.f; alo[j] = (_Float16)0.f; }
        if (lq < 2) {
            float4 x0 = *(const float4*)(xrow + 768 + lq * 8);
            float4 x1 = *(const float4*)(xrow + 768 + lq * 8 + 4);
            float xv[8] = { x0.x, x0.y, x0.z, x0.w, x1.x, x1.y, x1.z, x1.w };
            #pragma unroll
            for (int j = 0; j < 8; ++j) {
                _Float16 h = (_Float16)xv[j];
                ahi[j] = h;
                alo[j] = (_Float16)((xv[j] - (float)h) * LOSCALE);
            }
        }
        #pragma unroll
        for (int ct = 0; ct < 6; ++ct) {
            f16x8 bhi, blo;
            #pragma unroll
            for (int j = 0; j < 8; ++j) { bhi[j] = (_Float16)0.f; blo[j] = (_Float16)0.f; }
            if (lq < 2) {
                size_t off = (size_t)(n0 + ct * 16 + lr) * NIN + 768 + lq * 8;
                bhi = *(const f16x8*)(Wphi + off);
                blo = *(const f16x8*)(Wplo + off);
            }
            acc[ct] = __builtin_amdgcn_mfma_f32_16x16x32_f16(ahi, bhi, acc[ct], 0, 0, 0);
            acr[ct] = __builtin_amdgcn_mfma_f32_16x16x32_f16(ahi, blo, acr[ct], 0, 0, 0);
            acr[ct] = __builtin_amdgcn_mfma_f32_16x16x32_f16(alo, bhi, acr[ct], 0, 0, 0);
        }
    }
    int brow = b0 + w * 16 + lq * 4;
    #pragma unroll
    for (int ct = 0; ct < 6; ++ct) {
        int n = n0 + ct * 16 + lr;
        float bias = bp[n];
        #pragma unroll
        for (int r = 0; r < 4; ++r)
            pre[(size_t)(brow + r) * NH + n] = acc[ct][r] + LOINV * acr[ct][r] + bias;
    }
}

// ---------------------------------------------------------------------------
// Normalize + hi/lo split: y = a[j]*relu(pre)+c[j]; 8 elems/thread
__global__ __launch_bounds__(256) void norm_hl(
        const float* __restrict__ pre, const float* __restrict__ a,
        const float* __restrict__ c, _Float16* __restrict__ hi,
        _Float16* __restrict__ lo) {
    int idx = blockIdx.x * 256 + threadIdx.x;   // over B*NH/8
    int j = (idx * 8) % NH;
    float4 v0 = ((const float4*)pre)[idx * 2];
    float4 v1 = ((const float4*)pre)[idx * 2 + 1];
    float y[8] = {
        a[j+0] * fmaxf(v0.x, 0.f) + c[j+0], a[j+1] * fmaxf(v0.y, 0.f) + c[j+1],
        a[j+2] * fmaxf(v0.z, 0.f) + c[j+2], a[j+3] * fmaxf(v0.w, 0.f) + c[j+3],
        a[j+4] * fmaxf(v1.x, 0.f) + c[j+4], a[j+5] * fmaxf(v1.y, 0.f) + c[j+5],
        a[j+6] * fmaxf(v1.z, 0.f) + c[j+6], a[j+7] * fmaxf(v1.w, 0.f) + c[j+7] };
    f16x8 h8, l8;
    #pragma unroll
    for (int jj = 0; jj < 8; ++jj) {
        _Float16 h = (_Float16)y[jj];
        h8[jj] = h;
        l8[jj] = (_Float16)((y[jj] - (float)h) * LOSCALE);
    }
    *(f16x8*)(hi + (size_t)idx * 8) = h8;
    *(f16x8*)(lo + (size_t)idx * 8) = l8;
}

// ---------------------------------------------------------------------------
// Gates from reconstructed acts (hi + lo/2048): fp32 dot + clip.
__global__ __launch_bounds__(256) void gate_kernel(
        const _Float16* __restrict__ aHi, const _Float16* __restrict__ aLo,
        const float* __restrict__ Wg_l, float* __restrict__ gateT,
        float* __restrict__ tg, int firstLayer) {
    int lane = threadIdx.x & 63;
    int w = threadIdx.x >> 6;
    int b = blockIdx.x * 4 + w;
    float a[6];
    #pragma unroll
    for (int s = 0; s < 6; ++s) {
        size_t off = (size_t)b * NH + s * 64 + lane;
        a[s] = (float)aHi[off] + LOINV * (float)aLo[off];
    }
    float gsum = 0.f, gval = 0.f;
    #pragma unroll
    for (int s = 0; s < 6; ++s) {
        #pragma unroll
        for (int t = 0; t < 6; ++t) {
            float p = a[s] * Wg_l[(s * 6 + t) * 64 + lane];
            #pragma unroll
            for (int m = 1; m < 64; m <<= 1) p += __shfl_xor(p, m, 64);
            float gcl = fminf(fmaxf(p, 0.f), 1.f);
            gsum += gcl;
            if (lane == s * 6 + t) gval = gcl;
        }
    }
    if (lane < 36) gateT[(size_t)lane * BATCH + b] = gval;
    if (lane == 0) tg[b] = (firstLayer ? 0.f : tg[b]) + gsum;
}

// ---------------------------------------------------------------------------
// Routed layer (fp16x3 MFMA, transposed D^T[e][b]).
// grid (B/32, 2), block 256 (4 waves). Block: 32 batch rows, targets
// t0..t0+2 (t0 = blockIdx.y*3). Wave w: e-tile [w*16, w*16+16).
__global__ __launch_bounds__(256, 4) void layer_data_mfma(
        const _Float16* __restrict__ aHi, const _Float16* __restrict__ aLo,
        const float* __restrict__ gateT, const _Float16* __restrict__ Wdhi,
        const _Float16* __restrict__ Wdlo, const float* __restrict__ bd_l,
        float* __restrict__ pre) {
    int tid = threadIdx.x;
    int w = tid >> 6, l = tid & 63, lr = l & 15, lq = l >> 4;
    int b0 = blockIdx.x * 32;
    int t0 = blockIdx.y * 3;
    int e0 = w * 16;
    f32x4 acc[3][2];
    #pragma unroll
    for (int t = 0; t < 3; ++t)
        #pragma unroll
        for (int ct = 0; ct < 2; ++ct)
            #pragma unroll
            for (int r = 0; r < 4; ++r) acc[t][ct][r] = 0.f;
    for (int s = 0; s < 6; ++s) {
        f16x8 bhi[2][2], blo[2][2];   // [ct][ks]
        #pragma unroll
        for (int ct = 0; ct < 2; ++ct) {
            size_t arow = (size_t)(b0 + ct * 16 + lr) * NH + s * 64 + lq * 8;
            #pragma unroll
            for (int ks = 0; ks < 2; ++ks) {
                bhi[ct][ks] = *(const f16x8*)(aHi + arow + ks * 32);
                blo[ct][ks] = *(const f16x8*)(aLo + arow + ks * 32);
            }
        }
        #pragma unroll
        for (int tt = 0; tt < 3; ++tt) {
            int t = t0 + tt;
            float g0 = gateT[(size_t)(s * 6 + t) * BATCH + b0 + lr];
            float g1 = gateT[(size_t)(s * 6 + t) * BATCH + b0 + 16 + lr];
            size_t wb = ((size_t)(s * 6 + t) * 64 + e0 + lr) * 64 + lq * 8;
            f16x8 ah0 = *(const f16x8*)(Wdhi + wb);
            f16x8 ah1 = *(const f16x8*)(Wdhi + wb + 32);
            f16x8 al0 = *(const f16x8*)(Wdlo + wb);
            f16x8 al1 = *(const f16x8*)(Wdlo + wb + 32);
            float bdv[4];
            #pragma unroll
            for (int r = 0; r < 4; ++r)
                bdv[r] = bd_l[(s * 6 + t) * 64 + e0 + lq * 4 + r];
            #pragma unroll
            for (int ct = 0; ct < 2; ++ct) {
                f32x4 ph, pc;
                #pragma unroll
                for (int r = 0; r < 4; ++r) { ph[r] = 0.f; pc[r] = 0.f; }
                ph = __builtin_amdgcn_mfma_f32_16x16x32_f16(ah0, bhi[ct][0], ph, 0, 0, 0);
                ph = __builtin_amdgcn_mfma_f32_16x16x32_f16(ah1, bhi[ct][1], ph, 0, 0, 0);
                pc = __builtin_amdgcn_mfma_f32_16x16x32_f16(ah0, blo[ct][0], pc, 0, 0, 0);
                pc = __builtin_amdgcn_mfma_f32_16x16x32_f16(ah1, blo[ct][1], pc, 0, 0, 0);
                pc = __builtin_amdgcn_mfma_f32_16x16x32_f16(al0, bhi[ct][0], pc, 0, 0, 0);
                pc = __builtin_amdgcn_mfma_f32_16x16x32_f16(al1, bhi[ct][1], pc, 0, 0, 0);
                float g = ct ? g1 : g0;
                #pragma unroll
                for (int r = 0; r < 4; ++r)
                    acc[tt][ct][r] += g * (ph[r] + LOINV * pc[r] + bdv[r]);
            }
        }
    }
    #pragma unroll
    for (int tt = 0; tt < 3; ++tt)
        #pragma unroll
        for (int ct = 0; ct < 2; ++ct)
            #pragma unroll
            for (int r = 0; r < 4; ++r)
                pre[(size_t)(b0 + ct * 16 + lr) * NH + (t0 + tt) * 64 + e0 + lq * 4 + r]
                    = acc[tt][ct][r];
}

// ---------------------------------------------------------------------------
// Output head + total_gate copy (fp32 exact from reconstructed acts)
__global__ __launch_bounds__(256) void out_kernel(
        const _Float16* __restrict__ aHi, const _Float16* __restrict__ aLo,
        const float* __restrict__ W_out, const float* __restrict__ tg,
        float* __restrict__ dout) {
    int lane = threadIdx.x & 63;
    int w = threadIdx.x >> 6;
    int b = blockIdx.x * 4 + w;
    float a[6];
    #pragma unroll
    for (int s = 0; s < 6; ++s) {
        size_t off = (size_t)b * NH + s * 64 + lane;
        a[s] = (float)aHi[off] + LOINV * (float)aLo[off];
    }
    float ov = 0.f;
    #pragma unroll
    for (int o = 0; o < NOUT; ++o) {
        float p = 0.f;
        #pragma unroll
        for (int s = 0; s < 6; ++s) p += a[s] * W_out[(s * NOUT + o) * 64 + lane];
        #pragma unroll
        for (int m = 1; m < 64; m <<= 1) p += __shfl_xor(p, m, 64);
        if (lane == o) ov = p;
    }
    if (lane < NOUT) dout[(size_t)b * NOUT + lane] = ov;
    if (lane == 0) dout[(size_t)BATCH * NOUT + b] = tg[b];
}

// ---------------------------------------------------------------------------
extern "C" void kernel_launch(void* const* d_in, const int* in_sizes, int n_in,
                              void* d_out, int out_size, void* d_ws, size_t ws_size,
                              hipStream_t stream) {
    const float* x        = (const float*)d_in[0];
    const float* gamma_in = (const float*)d_in[1];
    const float* beta_in  = (const float*)d_in[2];
    const float* W_in     = (const float*)d_in[3];
    const float* b_in     = (const float*)d_in[4];
    const float* Wg       = (const float*)d_in[5];
    const float* Wd       = (const float*)d_in[6];
    const float* bd       = (const float*)d_in[7];
    const float* gamma_h  = (const float*)d_in[8];
    const float* beta_h   = (const float*)d_in[9];
    const float* W_out    = (const float*)d_in[10];
    float* dout = (float*)d_out;
    float* ws = (float*)d_ws;

    // workspace layout (float offsets), total 13,624,320 floats = 54.5 MiB
    float* psum  = ws;                          // 64*1024
    float* psq   = ws + 65536;                  // 64*1024
    float* avec  = ws + 131072;                 // 1024
    float* cvec  = ws + 132096;                 // 1024
    float* bp    = ws + 133120;                 // 1024
    float* pre   = ws + 134144;                 // B*NH f32
    _Float16* actsHi = (_Float16*)(ws + 6425600);   // B*NH f16
    _Float16* actsLo = (_Float16*)(ws + 9571328);   // B*NH f16
    float* gateT = ws + 12717056;               // 36*B f32
    float* tg    = ws + 13306880;               // B
    _Float16* WpHi = (_Float16*)(ws + 13323264);    // 384*784 f16
    _Float16* WpLo = (_Float16*)(ws + 13473792);    // 384*784 f16
    // per-layer Wd hi/lo buffers ALIAS the Wp region (Wp dead after gemm_in)
    _Float16* WdHiCur = WpHi;                   // 36*4096 f16 (fits)
    _Float16* WdLoCur = WpLo;

    dim3 blk(256);

    // ---- prep: input BN fold + weight split-cast
    stats_partial<<<dim3(4, NPART), blk, 0, stream>>>(x, NIN, 0, psum, psq);
    stats_finalize<<<dim3(4), blk, 0, stream>>>(psum, psq, NIN, gamma_in, beta_in, avec, cvec);
    scale_win_hl<<<dim3((NH * NIN / 4 + 255) / 256), blk, 0, stream>>>(W_in, avec, WpHi, WpLo);
    bias_in<<<dim3(NH), dim3(64), 0, stream>>>(W_in, b_in, cvec, bp);

    // ---- input GEMM (fp16x3 MFMA) -> pre f32
    gemm_in_mfma<<<dim3(BATCH / 64, 4), blk, 0, stream>>>(x, WpHi, WpLo, bp, pre);

    // ---- hidden layers
    for (int j = 0; j < NLAYERS; ++j) {
        stats_partial<<<dim3(2, NPART), blk, 0, stream>>>(pre, NH, 1, psum, psq);
        stats_finalize<<<dim3(2), blk, 0, stream>>>(psum, psq, NH,
                gamma_h + j * NH, beta_h + j * NH, avec, cvec);
        norm_hl<<<dim3(BATCH * NH / 8 / 256), blk, 0, stream>>>(pre, avec, cvec, actsHi, actsLo);
        if (j < NLAYERS - 1) {
            int l = j;
            conv_hl<<<dim3(144), blk, 0, stream>>>(
                    Wd + (size_t)l * 36 * 4096, WdHiCur, WdLoCur, 36 * 4096 / 4);
            gate_kernel<<<dim3(BATCH / 4), blk, 0, stream>>>(
                    actsHi, actsLo, Wg + (size_t)l * 36 * 64, gateT, tg, l == 0);
            layer_data_mfma<<<dim3(BATCH / 32, 2), blk, 0, stream>>>(
                    actsHi, actsLo, gateT, WdHiCur, WdLoCur,
                    bd + (size_t)l * 36 * 64, pre);
        }
    }

    // ---- output head + total_gate
    out_kernel<<<dim3(BATCH / 4), blk, 0, stream>>>(actsHi, actsLo, W_out, tg, dout);
}

// Round 6
// 876.949 us; speedup vs baseline: 1.5934x; 1.5934x over previous
//
#include <hip/hip_runtime.h>
#include <hip/hip_bf16.h>

#define BATCH   16384
#define NIN     784
#define NH      384
#define NLAYERS 6
#define NOUT    10
#define EPS_BN  1e-5f
#define LOSCALE 2048.0f
#define LOINV   (1.0f/2048.0f)
#define NPART   64
#define PSTRIDE 1024

typedef __attribute__((ext_vector_type(8))) _Float16 f16x8;
typedef __attribute__((ext_vector_type(4))) _Float16 f16x4;
typedef __attribute__((ext_vector_type(4))) float f32x4;

// ---------------------------------------------------------------------------
// Column stats (two-stage, deterministic).  src [B, C] f32 row-major.
__global__ __launch_bounds__(256) void stats_partial(
        const float* __restrict__ src, int C, int applyRelu,
        float* __restrict__ psum, float* __restrict__ psq) {
    int c = blockIdx.x * 256 + threadIdx.x;
    if (c >= C) return;
    int r0 = blockIdx.y * (BATCH / NPART);
    float s = 0.f, q = 0.f;
    for (int r = r0; r < r0 + BATCH / NPART; ++r) {
        float v = src[(size_t)r * C + c];
        if (applyRelu) v = fmaxf(v, 0.f);
        s += v; q += v * v;
    }
    psum[blockIdx.y * PSTRIDE + c] = s;
    psq [blockIdx.y * PSTRIDE + c] = q;
}

__global__ __launch_bounds__(256) void stats_finalize(
        const float* __restrict__ psum, const float* __restrict__ psq, int C,
        const float* __restrict__ gamma, const float* __restrict__ beta,
        float* __restrict__ a_out, float* __restrict__ c_out) {
    int c = blockIdx.x * 256 + threadIdx.x;
    if (c >= C) return;
    float s = 0.f, q = 0.f;
    for (int i = 0; i < NPART; ++i) { s += psum[i * PSTRIDE + c]; q += psq[i * PSTRIDE + c]; }
    const float invB = 1.f / (float)BATCH;
    float mu  = s * invB;
    float var = q * invB - mu * mu;
    float rs  = rsqrtf(var + EPS_BN);
    float g   = gamma[c];
    a_out[c] = g * rs;
    c_out[c] = beta[c] - g * mu * rs;
}

// ---------------------------------------------------------------------------
// Wp[j][n] = a[n]*W_in[j][n] split into f16 hi/lo(scaled).  4 elems/thread.
__global__ __launch_bounds__(256) void scale_win_hl(
        const float* __restrict__ W_in, const float* __restrict__ a,
        _Float16* __restrict__ whi, _Float16* __restrict__ wlo) {
    int i = blockIdx.x * 256 + threadIdx.x;
    if (i >= NH * NIN / 4) return;
    int n = (i * 4) % NIN;
    float4 wv = ((const float4*)W_in)[i];
    float v[4] = { wv.x * a[n], wv.y * a[n + 1], wv.z * a[n + 2], wv.w * a[n + 3] };
    f16x4 h4, l4;
    #pragma unroll
    for (int j = 0; j < 4; ++j) {
        _Float16 h = (_Float16)v[j];
        h4[j] = h;
        l4[j] = (_Float16)((v[j] - (float)h) * LOSCALE);
    }
    *(f16x4*)(whi + (size_t)i * 4) = h4;
    *(f16x4*)(wlo + (size_t)i * 4) = l4;
}

// f32 -> f16 hi/lo(scaled) split, 4 elems/thread (all Wd layers at once)
__global__ __launch_bounds__(256) void conv_hl(
        const float* __restrict__ src, _Float16* __restrict__ hi,
        _Float16* __restrict__ lo, int n4) {
    int i = blockIdx.x * 256 + threadIdx.x;
    if (i >= n4) return;
    float4 wv = ((const float4*)src)[i];
    float v[4] = { wv.x, wv.y, wv.z, wv.w };
    f16x4 h4, l4;
    #pragma unroll
    for (int j = 0; j < 4; ++j) {
        _Float16 h = (_Float16)v[j];
        h4[j] = h;
        l4[j] = (_Float16)((v[j] - (float)h) * LOSCALE);
    }
    *(f16x4*)(hi + (size_t)i * 4) = h4;
    *(f16x4*)(lo + (size_t)i * 4) = l4;
}

// Zero-padded gate weights: WgPad[l][st][k] (48 rows, 384 cols), support only
// where k>>6 == st/6.  One elem/thread over 5*48*384.
__global__ __launch_bounds__(256) void prep_wg(
        const float* __restrict__ Wg, _Float16* __restrict__ hi,
        _Float16* __restrict__ lo) {
    int idx = blockIdx.x * 256 + threadIdx.x;
    if (idx >= 5 * 48 * 384) return;
    int l = idx / (48 * 384);
    int r = idx % (48 * 384);
    int st = r / 384, k = r % 384;
    float v = 0.f;
    if (st < 36 && (k >> 6) == st / 6)
        v = Wg[l * 36 * 64 + st * 64 + (k & 63)];
    _Float16 h = (_Float16)v;
    hi[idx] = h;
    lo[idx] = (_Float16)((v - (float)h) * LOSCALE);
}

// Padded output weights: OutPad[o][k] (16 rows x 384), o<10: W_out[s][o][d],
// k = s*64+d (full support).  One elem/thread over 16*384.
__global__ __launch_bounds__(256) void prep_wout(
        const float* __restrict__ W_out, _Float16* __restrict__ hi,
        _Float16* __restrict__ lo) {
    int idx = blockIdx.x * 256 + threadIdx.x;
    if (idx >= 16 * 384) return;
    int o = idx / 384, k = idx % 384;
    float v = 0.f;
    if (o < NOUT) v = W_out[((k >> 6) * NOUT + o) * 64 + (k & 63)];
    _Float16 h = (_Float16)v;
    hi[idx] = h;
    lo[idx] = (_Float16)((v - (float)h) * LOSCALE);
}

// b'[j] = b_in[j] + sum_n c[n]*W_in[j,n]  (f32, exact)
__global__ __launch_bounds__(64) void bias_in(
        const float* __restrict__ W_in, const float* __restrict__ b_in,
        const float* __restrict__ cvec, float* __restrict__ bp) {
    int j = blockIdx.x;
    int lane = threadIdx.x;
    float s = 0.f;
    for (int n = lane; n < NIN; n += 64) s += cvec[n] * W_in[j * NIN + n];
    #pragma unroll
    for (int m = 1; m < 64; m <<= 1) s += __shfl_xor(s, m, 64);
    if (lane == 0) bp[j] = b_in[j] + s;
}

// ---------------------------------------------------------------------------
// Input GEMM (fp16x3 MFMA): pre[b,j] = X[b,:].Wp[j,:] + bp[j]
// grid (256, 4), block 256. Wave: 16 batch rows x 96 n-cols (ct=6).
__global__ __launch_bounds__(256, 2) void gemm_in_mfma(
        const float* __restrict__ X, const _Float16* __restrict__ Wphi,
        const _Float16* __restrict__ Wplo, const float* __restrict__ bp,
        float* __restrict__ pre) {
    int tid = threadIdx.x;
    int w = tid >> 6, l = tid & 63, lr = l & 15, lq = l >> 4;
    int b0 = blockIdx.x * 64;
    int n0 = blockIdx.y * 96;
    const float* xrow = X + (size_t)(b0 + w * 16 + lr) * NIN;
    f32x4 acc[6], acr[6];
    #pragma unroll
    for (int ct = 0; ct < 6; ++ct)
        #pragma unroll
        for (int r = 0; r < 4; ++r) { acc[ct][r] = 0.f; acr[ct][r] = 0.f; }
    for (int kc = 0; kc < 24; ++kc) {
        int k0 = kc * 32 + lq * 8;
        float4 x0 = *(const float4*)(xrow + k0);
        float4 x1 = *(const float4*)(xrow + k0 + 4);
        float xv[8] = { x0.x, x0.y, x0.z, x0.w, x1.x, x1.y, x1.z, x1.w };
        f16x8 ahi, alo;
        #pragma unroll
        for (int j = 0; j < 8; ++j) {
            _Float16 h = (_Float16)xv[j];
            ahi[j] = h;
            alo[j] = (_Float16)((xv[j] - (float)h) * LOSCALE);
        }
        #pragma unroll
        for (int ct = 0; ct < 6; ++ct) {
            size_t off = (size_t)(n0 + ct * 16 + lr) * NIN + k0;
            f16x8 bhi = *(const f16x8*)(Wphi + off);
            f16x8 blo = *(const f16x8*)(Wplo + off);
            acc[ct] = __builtin_amdgcn_mfma_f32_16x16x32_f16(ahi, bhi, acc[ct], 0, 0, 0);
            acr[ct] = __builtin_amdgcn_mfma_f32_16x16x32_f16(ahi, blo, acr[ct], 0, 0, 0);
            acr[ct] = __builtin_amdgcn_mfma_f32_16x16x32_f16(alo, bhi, acr[ct], 0, 0, 0);
        }
    }
    {   // K tail 768..783 (16 valid): lanes lq>=2 contribute zeros
        f16x8 ahi, alo;
        #pragma unroll
        for (int j = 0; j < 8; ++j) { ahi[j] = (_Float16)0.f; alo[j] = (_Float16)0.f; }
        if (lq < 2) {
            float4 x0 = *(const float4*)(xrow + 768 + lq * 8);
            float4 x1 = *(const float4*)(xrow + 768 + lq * 8 + 4);
            float xv[8] = { x0.x, x0.y, x0.z, x0.w, x1.x, x1.y, x1.z, x1.w };
            #pragma unroll
            for (int j = 0; j < 8; ++j) {
                _Float16 h = (_Float16)xv[j];
                ahi[j] = h;
                alo[j] = (_Float16)((xv[j] - (float)h) * LOSCALE);
            }
        }
        #pragma unroll
        for (int ct = 0; ct < 6; ++ct) {
            f16x8 bhi, blo;
            #pragma unroll
            for (int j = 0; j < 8; ++j) { bhi[j] = (_Float16)0.f; blo[j] = (_Float16)0.f; }
            if (lq < 2) {
                size_t off = (size_t)(n0 + ct * 16 + lr) * NIN + 768 + lq * 8;
                bhi = *(const f16x8*)(Wphi + off);
                blo = *(const f16x8*)(Wplo + off);
            }
            acc[ct] = __builtin_amdgcn_mfma_f32_16x16x32_f16(ahi, bhi, acc[ct], 0, 0, 0);
            acr[ct] = __builtin_amdgcn_mfma_f32_16x16x32_f16(ahi, blo, acr[ct], 0, 0, 0);
            acr[ct] = __builtin_amdgcn_mfma_f32_16x16x32_f16(alo, bhi, acr[ct], 0, 0, 0);
        }
    }
    int brow = b0 + w * 16 + lq * 4;
    #pragma unroll
    for (int ct = 0; ct < 6; ++ct) {
        int n = n0 + ct * 16 + lr;
        float bias = bp[n];
        #pragma unroll
        for (int r = 0; r < 4; ++r)
            pre[(size_t)(brow + r) * NH + n] = acc[ct][r] + LOINV * acr[ct][r] + bias;
    }
}

// ---------------------------------------------------------------------------
// Normalize + hi/lo split: y = a[j]*relu(pre)+c[j]; 8 elems/thread
__global__ __launch_bounds__(256) void norm_hl(
        const float* __restrict__ pre, const float* __restrict__ a,
        const float* __restrict__ c, _Float16* __restrict__ hi,
        _Float16* __restrict__ lo) {
    int idx = blockIdx.x * 256 + threadIdx.x;   // over B*NH/8
    int j = (idx * 8) % NH;
    float4 v0 = ((const float4*)pre)[idx * 2];
    float4 v1 = ((const float4*)pre)[idx * 2 + 1];
    float y[8] = {
        a[j+0] * fmaxf(v0.x, 0.f) + c[j+0], a[j+1] * fmaxf(v0.y, 0.f) + c[j+1],
        a[j+2] * fmaxf(v0.z, 0.f) + c[j+2], a[j+3] * fmaxf(v0.w, 0.f) + c[j+3],
        a[j+4] * fmaxf(v1.x, 0.f) + c[j+4], a[j+5] * fmaxf(v1.y, 0.f) + c[j+5],
        a[j+6] * fmaxf(v1.z, 0.f) + c[j+6], a[j+7] * fmaxf(v1.w, 0.f) + c[j+7] };
    f16x8 h8, l8;
    #pragma unroll
    for (int jj = 0; jj < 8; ++jj) {
        _Float16 h = (_Float16)y[jj];
        h8[jj] = h;
        l8[jj] = (_Float16)((y[jj] - (float)h) * LOSCALE);
    }
    *(f16x8*)(hi + (size_t)idx * 8) = h8;
    *(f16x8*)(lo + (size_t)idx * 8) = l8;
}

// ---------------------------------------------------------------------------
// Gate GEMM (fp16x3 MFMA): gateT[st][b] = clip(acts[b,:].WgPad[st,:], 0, 1);
// tg[b] (+)= sum_st gate.  grid B/64, block 256; wave: 48 st-rows x 16 b-cols.
__global__ __launch_bounds__(256, 2) void gate_mfma(
        const _Float16* __restrict__ aHi, const _Float16* __restrict__ aLo,
        const _Float16* __restrict__ WgHi, const _Float16* __restrict__ WgLo,
        float* __restrict__ gateT, float* __restrict__ tg, int firstLayer) {
    int tid = threadIdx.x;
    int w = tid >> 6, l = tid & 63, lr = l & 15, lq = l >> 4;
    int b = blockIdx.x * 64 + w * 16 + lr;
    const _Float16* arowH = aHi + (size_t)b * NH;
    const _Float16* arowL = aLo + (size_t)b * NH;
    f32x4 acc[3], acr[3];
    #pragma unroll
    for (int rt = 0; rt < 3; ++rt)
        #pragma unroll
        for (int r = 0; r < 4; ++r) { acc[rt][r] = 0.f; acr[rt][r] = 0.f; }
    #pragma unroll
    for (int kc = 0; kc < 12; ++kc) {
        int k0 = kc * 32 + lq * 8;
        f16x8 bhi = *(const f16x8*)(arowH + k0);
        f16x8 blo = *(const f16x8*)(arowL + k0);
        #pragma unroll
        for (int rt = 0; rt < 3; ++rt) {
            size_t off = (size_t)(rt * 16 + lr) * NH + k0;
            f16x8 ahi = *(const f16x8*)(WgHi + off);
            f16x8 alo = *(const f16x8*)(WgLo + off);
            acc[rt] = __builtin_amdgcn_mfma_f32_16x16x32_f16(ahi, bhi, acc[rt], 0, 0, 0);
            acr[rt] = __builtin_amdgcn_mfma_f32_16x16x32_f16(ahi, blo, acr[rt], 0, 0, 0);
            acr[rt] = __builtin_amdgcn_mfma_f32_16x16x32_f16(alo, bhi, acr[rt], 0, 0, 0);
        }
    }
    float gsum = 0.f;
    #pragma unroll
    for (int rt = 0; rt < 3; ++rt)
        #pragma unroll
        for (int r = 0; r < 4; ++r) {
            int st = rt * 16 + lq * 4 + r;
            if (st < 36) {
                float p = acc[rt][r] + LOINV * acr[rt][r];
                float g = fminf(fmaxf(p, 0.f), 1.f);
                gateT[(size_t)st * BATCH + b] = g;
                gsum += g;
            }
        }
    gsum += __shfl_xor(gsum, 16, 64);
    gsum += __shfl_xor(gsum, 32, 64);
    if (lq == 0) tg[b] = (firstLayer ? 0.f : tg[b]) + gsum;
}

// ---------------------------------------------------------------------------
// Routed layer (fp16x3 MFMA, transposed D^T[e][b]).
// grid (B/32, 2), block 256 (4 waves). Block: 32 batch rows, targets
// t0..t0+2 (t0 = blockIdx.y*3). Wave w: e-tile [w*16, w*16+16).
__global__ __launch_bounds__(256, 2) void layer_data_mfma(
        const _Float16* __restrict__ aHi, const _Float16* __restrict__ aLo,
        const float* __restrict__ gateT, const _Float16* __restrict__ Wdhi,
        const _Float16* __restrict__ Wdlo, const float* __restrict__ bd_l,
        float* __restrict__ pre) {
    int tid = threadIdx.x;
    int w = tid >> 6, l = tid & 63, lr = l & 15, lq = l >> 4;
    int b0 = blockIdx.x * 32;
    int t0 = blockIdx.y * 3;
    int e0 = w * 16;
    f32x4 acc[3][2];
    #pragma unroll
    for (int t = 0; t < 3; ++t)
        #pragma unroll
        for (int ct = 0; ct < 2; ++ct)
            #pragma unroll
            for (int r = 0; r < 4; ++r) acc[t][ct][r] = 0.f;
    for (int s = 0; s < 6; ++s) {
        f16x8 bhi[2][2], blo[2][2];   // [ct][ks]
        #pragma unroll
        for (int ct = 0; ct < 2; ++ct) {
            size_t arow = (size_t)(b0 + ct * 16 + lr) * NH + s * 64 + lq * 8;
            #pragma unroll
            for (int ks = 0; ks < 2; ++ks) {
                bhi[ct][ks] = *(const f16x8*)(aHi + arow + ks * 32);
                blo[ct][ks] = *(const f16x8*)(aLo + arow + ks * 32);
            }
        }
        #pragma unroll
        for (int tt = 0; tt < 3; ++tt) {
            int t = t0 + tt;
            float g0 = gateT[(size_t)(s * 6 + t) * BATCH + b0 + lr];
            float g1 = gateT[(size_t)(s * 6 + t) * BATCH + b0 + 16 + lr];
            size_t wb = ((size_t)(s * 6 + t) * 64 + e0 + lr) * 64 + lq * 8;
            f16x8 ah0 = *(const f16x8*)(Wdhi + wb);
            f16x8 ah1 = *(const f16x8*)(Wdhi + wb + 32);
            f16x8 al0 = *(const f16x8*)(Wdlo + wb);
            f16x8 al1 = *(const f16x8*)(Wdlo + wb + 32);
            float bdv[4];
            #pragma unroll
            for (int r = 0; r < 4; ++r)
                bdv[r] = bd_l[(s * 6 + t) * 64 + e0 + lq * 4 + r];
            #pragma unroll
            for (int ct = 0; ct < 2; ++ct) {
                f32x4 ph, pc;
                #pragma unroll
                for (int r = 0; r < 4; ++r) { ph[r] = 0.f; pc[r] = 0.f; }
                ph = __builtin_amdgcn_mfma_f32_16x16x32_f16(ah0, bhi[ct][0], ph, 0, 0, 0);
                ph = __builtin_amdgcn_mfma_f32_16x16x32_f16(ah1, bhi[ct][1], ph, 0, 0, 0);
                pc = __builtin_amdgcn_mfma_f32_16x16x32_f16(ah0, blo[ct][0], pc, 0, 0, 0);
                pc = __builtin_amdgcn_mfma_f32_16x16x32_f16(ah1, blo[ct][1], pc, 0, 0, 0);
                pc = __builtin_amdgcn_mfma_f32_16x16x32_f16(al0, bhi[ct][0], pc, 0, 0, 0);
                pc = __builtin_amdgcn_mfma_f32_16x16x32_f16(al1, bhi[ct][1], pc, 0, 0, 0);
                float g = ct ? g1 : g0;
                #pragma unroll
                for (int r = 0; r < 4; ++r)
                    acc[tt][ct][r] += g * (ph[r] + LOINV * pc[r] + bdv[r]);
            }
        }
    }
    #pragma unroll
    for (int tt = 0; tt < 3; ++tt)
        #pragma unroll
        for (int ct = 0; ct < 2; ++ct)
            #pragma unroll
            for (int r = 0; r < 4; ++r)
                pre[(size_t)(b0 + ct * 16 + lr) * NH + (t0 + tt) * 64 + e0 + lq * 4 + r]
                    = acc[tt][ct][r];
}

// ---------------------------------------------------------------------------
// Output head GEMM (fp16x3 MFMA): out[b,o] = acts[b,:].OutPad[o,:] (o<10);
// + tg copy.  grid B/64, block 256; wave: 16 o-rows x 16 b-cols.
__global__ __launch_bounds__(256, 2) void out_mfma(
        const _Float16* __restrict__ aHi, const _Float16* __restrict__ aLo,
        const _Float16* __restrict__ OutHi, const _Float16* __restrict__ OutLo,
        const float* __restrict__ tg, float* __restrict__ dout) {
    int tid = threadIdx.x;
    int w = tid >> 6, l = tid & 63, lr = l & 15, lq = l >> 4;
    int b = blockIdx.x * 64 + w * 16 + lr;
    const _Float16* arowH = aHi + (size_t)b * NH;
    const _Float16* arowL = aLo + (size_t)b * NH;
    f32x4 acc, acr;
    #pragma unroll
    for (int r = 0; r < 4; ++r) { acc[r] = 0.f; acr[r] = 0.f; }
    #pragma unroll
    for (int kc = 0; kc < 12; ++kc) {
        int k0 = kc * 32 + lq * 8;
        f16x8 bhi = *(const f16x8*)(arowH + k0);
        f16x8 blo = *(const f16x8*)(arowL + k0);
        size_t off = (size_t)lr * NH + k0;
        f16x8 ahi = *(const f16x8*)(OutHi + off);
        f16x8 alo = *(const f16x8*)(OutLo + off);
        acc = __builtin_amdgcn_mfma_f32_16x16x32_f16(ahi, bhi, acc, 0, 0, 0);
        acr = __builtin_amdgcn_mfma_f32_16x16x32_f16(ahi, blo, acr, 0, 0, 0);
        acr = __builtin_amdgcn_mfma_f32_16x16x32_f16(alo, bhi, acr, 0, 0, 0);
    }
    #pragma unroll
    for (int r = 0; r < 4; ++r) {
        int o = lq * 4 + r;
        if (o < NOUT)
            dout[(size_t)b * NOUT + o] = acc[r] + LOINV * acr[r];
    }
    if (lq == 0) dout[(size_t)BATCH * NOUT + b] = tg[b];
}

// ---------------------------------------------------------------------------
extern "C" void kernel_launch(void* const* d_in, const int* in_sizes, int n_in,
                              void* d_out, int out_size, void* d_ws, size_t ws_size,
                              hipStream_t stream) {
    const float* x        = (const float*)d_in[0];
    const float* gamma_in = (const float*)d_in[1];
    const float* beta_in  = (const float*)d_in[2];
    const float* W_in     = (const float*)d_in[3];
    const float* b_in     = (const float*)d_in[4];
    const float* Wg       = (const float*)d_in[5];
    const float* Wd       = (const float*)d_in[6];
    const float* bd       = (const float*)d_in[7];
    const float* gamma_h  = (const float*)d_in[8];
    const float* beta_h   = (const float*)d_in[9];
    const float* W_out    = (const float*)d_in[10];
    float* dout = (float*)d_out;
    float* ws = (float*)d_ws;

    // workspace layout (float offsets), total ~14.46M floats = 57.8 MiB
    float* psum  = ws;                              // 64*1024
    float* psq   = ws + 65536;                      // 64*1024
    float* avec  = ws + 131072;                     // 1024
    float* cvec  = ws + 132096;                     // 1024
    float* bp    = ws + 133120;                     // 1024
    float* pre   = ws + 134144;                     // B*NH f32
    _Float16* actsHi = (_Float16*)(ws + 6425600);   // B*NH f16
    _Float16* actsLo = (_Float16*)(ws + 9571328);   // B*NH f16
    float* gateT = ws + 12717056;                   // 36*B f32
    float* tg    = ws + 13306880;                   // B
    _Float16* WpHi = (_Float16*)(ws + 13323264);    // 384*784 f16
    _Float16* WpLo = (_Float16*)(ws + 13473792);    // 384*784 f16
    _Float16* WdHiAll = (_Float16*)(ws + 13624320); // 5*36*4096 f16
    _Float16* WdLoAll = (_Float16*)(ws + 13992960); // 5*36*4096 f16
    _Float16* WgHiAll = (_Float16*)(ws + 14361600); // 5*48*384 f16
    _Float16* WgLoAll = (_Float16*)(ws + 14407680); // 5*48*384 f16
    _Float16* OutHi   = (_Float16*)(ws + 14453760); // 16*384 f16
    _Float16* OutLo   = (_Float16*)(ws + 14456832); // 16*384 f16

    dim3 blk(256);

    // ---- prep: input BN fold + all weight split-casts (up front)
    stats_partial<<<dim3(4, NPART), blk, 0, stream>>>(x, NIN, 0, psum, psq);
    stats_finalize<<<dim3(4), blk, 0, stream>>>(psum, psq, NIN, gamma_in, beta_in, avec, cvec);
    scale_win_hl<<<dim3((NH * NIN / 4 + 255) / 256), blk, 0, stream>>>(W_in, avec, WpHi, WpLo);
    bias_in<<<dim3(NH), dim3(64), 0, stream>>>(W_in, b_in, cvec, bp);
    conv_hl<<<dim3((5 * 36 * 4096 / 4 + 255) / 256), blk, 0, stream>>>(
            Wd, WdHiAll, WdLoAll, 5 * 36 * 4096 / 4);
    prep_wg<<<dim3((5 * 48 * 384 + 255) / 256), blk, 0, stream>>>(Wg, WgHiAll, WgLoAll);
    prep_wout<<<dim3((16 * 384 + 255) / 256), blk, 0, stream>>>(W_out, OutHi, OutLo);

    // ---- input GEMM (fp16x3 MFMA) -> pre f32
    gemm_in_mfma<<<dim3(BATCH / 64, 4), blk, 0, stream>>>(x, WpHi, WpLo, bp, pre);

    // ---- hidden layers
    for (int j = 0; j < NLAYERS; ++j) {
        stats_partial<<<dim3(2, NPART), blk, 0, stream>>>(pre, NH, 1, psum, psq);
        stats_finalize<<<dim3(2), blk, 0, stream>>>(psum, psq, NH,
                gamma_h + j * NH, beta_h + j * NH, avec, cvec);
        norm_hl<<<dim3(BATCH * NH / 8 / 256), blk, 0, stream>>>(pre, avec, cvec, actsHi, actsLo);
        if (j < NLAYERS - 1) {
            int l = j;
            gate_mfma<<<dim3(BATCH / 64), blk, 0, stream>>>(
                    actsHi, actsLo, WgHiAll + (size_t)l * 48 * 384,
                    WgLoAll + (size_t)l * 48 * 384, gateT, tg, l == 0);
            layer_data_mfma<<<dim3(BATCH / 32, 2), blk, 0, stream>>>(
                    actsHi, actsLo, gateT, WdHiAll + (size_t)l * 36 * 4096,
                    WdLoAll + (size_t)l * 36 * 4096, bd + (size_t)l * 36 * 64, pre);
        }
    }

    // ---- output head + total_gate
    out_mfma<<<dim3(BATCH / 64), blk, 0, stream>>>(actsHi, actsLo, OutHi, OutLo, tg, dout);
}

// Round 7
// 620.581 us; speedup vs baseline: 2.2516x; 1.4131x over previous
//
#include <hip/hip_runtime.h>
#include <hip/hip_bf16.h>

#define BATCH   16384
#define NIN     784
#define NH      384
#define NLAYERS 6
#define NOUT    10
#define EPS_BN  1e-5f
#define LOSCALE 2048.0f
#define LOINV   (1.0f/2048.0f)
#define NPART   128
#define PSTRIDE 1024

typedef __attribute__((ext_vector_type(8))) _Float16 f16x8;
typedef __attribute__((ext_vector_type(4))) _Float16 f16x4;
typedef __attribute__((ext_vector_type(4))) float f32x4;

// ---------------------------------------------------------------------------
// Column stats (two-stage, deterministic).  src [B, C] f32 row-major.
__global__ __launch_bounds__(256) void stats_partial(
        const float* __restrict__ src, int C, int applyRelu,
        float* __restrict__ psum, float* __restrict__ psq) {
    int c = blockIdx.x * 256 + threadIdx.x;
    if (c >= C) return;
    int r0 = blockIdx.y * (BATCH / NPART);
    float s = 0.f, q = 0.f;
    for (int r = r0; r < r0 + BATCH / NPART; ++r) {
        float v = src[(size_t)r * C + c];
        if (applyRelu) v = fmaxf(v, 0.f);
        s += v; q += v * v;
    }
    psum[blockIdx.y * PSTRIDE + c] = s;
    psq [blockIdx.y * PSTRIDE + c] = q;
}

__global__ __launch_bounds__(256) void stats_finalize(
        const float* __restrict__ psum, const float* __restrict__ psq, int C,
        const float* __restrict__ gamma, const float* __restrict__ beta,
        float* __restrict__ a_out, float* __restrict__ c_out) {
    int c = blockIdx.x * 256 + threadIdx.x;
    if (c >= C) return;
    float s = 0.f, q = 0.f;
    for (int i = 0; i < NPART; ++i) { s += psum[i * PSTRIDE + c]; q += psq[i * PSTRIDE + c]; }
    const float invB = 1.f / (float)BATCH;
    float mu  = s * invB;
    float var = q * invB - mu * mu;
    float rs  = rsqrtf(var + EPS_BN);
    float g   = gamma[c];
    a_out[c] = g * rs;
    c_out[c] = beta[c] - g * mu * rs;
}

// ---------------------------------------------------------------------------
// Wp[j][n] = a[n]*W_in[j][n] split into f16 hi/lo(scaled).  4 elems/thread.
__global__ __launch_bounds__(256) void scale_win_hl(
        const float* __restrict__ W_in, const float* __restrict__ a,
        _Float16* __restrict__ whi, _Float16* __restrict__ wlo) {
    int i = blockIdx.x * 256 + threadIdx.x;
    if (i >= NH * NIN / 4) return;
    int n = (i * 4) % NIN;
    float4 wv = ((const float4*)W_in)[i];
    float v[4] = { wv.x * a[n], wv.y * a[n + 1], wv.z * a[n + 2], wv.w * a[n + 3] };
    f16x4 h4, l4;
    #pragma unroll
    for (int j = 0; j < 4; ++j) {
        _Float16 h = (_Float16)v[j];
        h4[j] = h;
        l4[j] = (_Float16)((v[j] - (float)h) * LOSCALE);
    }
    *(f16x4*)(whi + (size_t)i * 4) = h4;
    *(f16x4*)(wlo + (size_t)i * 4) = l4;
}

// f32 -> f16 hi/lo(scaled) split, 4 elems/thread (all Wd layers at once)
__global__ __launch_bounds__(256) void conv_hl(
        const float* __restrict__ src, _Float16* __restrict__ hi,
        _Float16* __restrict__ lo, int n4) {
    int i = blockIdx.x * 256 + threadIdx.x;
    if (i >= n4) return;
    float4 wv = ((const float4*)src)[i];
    float v[4] = { wv.x, wv.y, wv.z, wv.w };
    f16x4 h4, l4;
    #pragma unroll
    for (int j = 0; j < 4; ++j) {
        _Float16 h = (_Float16)v[j];
        h4[j] = h;
        l4[j] = (_Float16)((v[j] - (float)h) * LOSCALE);
    }
    *(f16x4*)(hi + (size_t)i * 4) = h4;
    *(f16x4*)(lo + (size_t)i * 4) = l4;
}

// Zero-padded gate weights: WgPad[l][st][k] (48 rows, 384 cols)
__global__ __launch_bounds__(256) void prep_wg(
        const float* __restrict__ Wg, _Float16* __restrict__ hi,
        _Float16* __restrict__ lo) {
    int idx = blockIdx.x * 256 + threadIdx.x;
    if (idx >= 5 * 48 * 384) return;
    int l = idx / (48 * 384);
    int r = idx % (48 * 384);
    int st = r / 384, k = r % 384;
    float v = 0.f;
    if (st < 36 && (k >> 6) == st / 6)
        v = Wg[l * 36 * 64 + st * 64 + (k & 63)];
    _Float16 h = (_Float16)v;
    hi[idx] = h;
    lo[idx] = (_Float16)((v - (float)h) * LOSCALE);
}

// Padded output weights: OutPad[o][k] (16 rows x 384)
__global__ __launch_bounds__(256) void prep_wout(
        const float* __restrict__ W_out, _Float16* __restrict__ hi,
        _Float16* __restrict__ lo) {
    int idx = blockIdx.x * 256 + threadIdx.x;
    if (idx >= 16 * 384) return;
    int o = idx / 384, k = idx % 384;
    float v = 0.f;
    if (o < NOUT) v = W_out[((k >> 6) * NOUT + o) * 64 + (k & 63)];
    _Float16 h = (_Float16)v;
    hi[idx] = h;
    lo[idx] = (_Float16)((v - (float)h) * LOSCALE);
}

// b'[j] = b_in[j] + sum_n c[n]*W_in[j,n]  (f32, exact)
__global__ __launch_bounds__(64) void bias_in(
        const float* __restrict__ W_in, const float* __restrict__ b_in,
        const float* __restrict__ cvec, float* __restrict__ bp) {
    int j = blockIdx.x;
    int lane = threadIdx.x;
    float s = 0.f;
    for (int n = lane; n < NIN; n += 64) s += cvec[n] * W_in[j * NIN + n];
    #pragma unroll
    for (int m = 1; m < 64; m <<= 1) s += __shfl_xor(s, m, 64);
    if (lane == 0) bp[j] = b_in[j] + s;
}

// ---------------------------------------------------------------------------
// Input GEMM (fp16x3 MFMA): pre[b,j] = X[b,:].Wp[j,:] + bp[j]
// grid (B/128, 4), block 256 (4 waves). Wave: 32 batch rows (bt=2) x 96 cols.
__global__ __launch_bounds__(256, 2) void gemm_in_mfma(
        const float* __restrict__ X, const _Float16* __restrict__ Wphi,
        const _Float16* __restrict__ Wplo, const float* __restrict__ bp,
        float* __restrict__ pre) {
    int tid = threadIdx.x;
    int w = tid >> 6, l = tid & 63, lr = l & 15, lq = l >> 4;
    int b0 = blockIdx.x * 128 + w * 32;
    int n0 = blockIdx.y * 96;
    const float* xrow0 = X + (size_t)(b0 + lr) * NIN;
    const float* xrow1 = X + (size_t)(b0 + 16 + lr) * NIN;
    f32x4 acc[6][2], acr[6][2];
    #pragma unroll
    for (int ct = 0; ct < 6; ++ct)
        #pragma unroll
        for (int bt = 0; bt < 2; ++bt)
            #pragma unroll
            for (int r = 0; r < 4; ++r) { acc[ct][bt][r] = 0.f; acr[ct][bt][r] = 0.f; }
    for (int kc = 0; kc < 24; ++kc) {
        int k0 = kc * 32 + lq * 8;
        f16x8 ahi[2], alo[2];
        {
            float4 x0 = *(const float4*)(xrow0 + k0);
            float4 x1 = *(const float4*)(xrow0 + k0 + 4);
            float xv[8] = { x0.x, x0.y, x0.z, x0.w, x1.x, x1.y, x1.z, x1.w };
            #pragma unroll
            for (int j = 0; j < 8; ++j) {
                _Float16 h = (_Float16)xv[j];
                ahi[0][j] = h;
                alo[0][j] = (_Float16)((xv[j] - (float)h) * LOSCALE);
            }
            float4 y0 = *(const float4*)(xrow1 + k0);
            float4 y1 = *(const float4*)(xrow1 + k0 + 4);
            float yv[8] = { y0.x, y0.y, y0.z, y0.w, y1.x, y1.y, y1.z, y1.w };
            #pragma unroll
            for (int j = 0; j < 8; ++j) {
                _Float16 h = (_Float16)yv[j];
                ahi[1][j] = h;
                alo[1][j] = (_Float16)((yv[j] - (float)h) * LOSCALE);
            }
        }
        #pragma unroll
        for (int ct = 0; ct < 6; ++ct) {
            size_t off = (size_t)(n0 + ct * 16 + lr) * NIN + k0;
            f16x8 bhi = *(const f16x8*)(Wphi + off);
            f16x8 blo = *(const f16x8*)(Wplo + off);
            #pragma unroll
            for (int bt = 0; bt < 2; ++bt) {
                acc[ct][bt] = __builtin_amdgcn_mfma_f32_16x16x32_f16(ahi[bt], bhi, acc[ct][bt], 0, 0, 0);
                acr[ct][bt] = __builtin_amdgcn_mfma_f32_16x16x32_f16(ahi[bt], blo, acr[ct][bt], 0, 0, 0);
                acr[ct][bt] = __builtin_amdgcn_mfma_f32_16x16x32_f16(alo[bt], bhi, acr[ct][bt], 0, 0, 0);
            }
        }
    }
    {   // K tail 768..783 (16 valid): lanes lq>=2 contribute zeros
        f16x8 ahi[2], alo[2];
        #pragma unroll
        for (int bt = 0; bt < 2; ++bt)
            #pragma unroll
            for (int j = 0; j < 8; ++j) { ahi[bt][j] = (_Float16)0.f; alo[bt][j] = (_Float16)0.f; }
        if (lq < 2) {
            const float* xr[2] = { xrow0, xrow1 };
            #pragma unroll
            for (int bt = 0; bt < 2; ++bt) {
                float4 x0 = *(const float4*)(xr[bt] + 768 + lq * 8);
                float4 x1 = *(const float4*)(xr[bt] + 768 + lq * 8 + 4);
                float xv[8] = { x0.x, x0.y, x0.z, x0.w, x1.x, x1.y, x1.z, x1.w };
                #pragma unroll
                for (int j = 0; j < 8; ++j) {
                    _Float16 h = (_Float16)xv[j];
                    ahi[bt][j] = h;
                    alo[bt][j] = (_Float16)((xv[j] - (float)h) * LOSCALE);
                }
            }
        }
        #pragma unroll
        for (int ct = 0; ct < 6; ++ct) {
            f16x8 bhi, blo;
            #pragma unroll
            for (int j = 0; j < 8; ++j) { bhi[j] = (_Float16)0.f; blo[j] = (_Float16)0.f; }
            if (lq < 2) {
                size_t off = (size_t)(n0 + ct * 16 + lr) * NIN + 768 + lq * 8;
                bhi = *(const f16x8*)(Wphi + off);
                blo = *(const f16x8*)(Wplo + off);
            }
            #pragma unroll
            for (int bt = 0; bt < 2; ++bt) {
                acc[ct][bt] = __builtin_amdgcn_mfma_f32_16x16x32_f16(ahi[bt], bhi, acc[ct][bt], 0, 0, 0);
                acr[ct][bt] = __builtin_amdgcn_mfma_f32_16x16x32_f16(ahi[bt], blo, acr[ct][bt], 0, 0, 0);
                acr[ct][bt] = __builtin_amdgcn_mfma_f32_16x16x32_f16(alo[bt], bhi, acr[ct][bt], 0, 0, 0);
            }
        }
    }
    #pragma unroll
    for (int ct = 0; ct < 6; ++ct) {
        int n = n0 + ct * 16 + lr;
        float bias = bp[n];
        #pragma unroll
        for (int bt = 0; bt < 2; ++bt) {
            int brow = b0 + bt * 16 + lq * 4;
            #pragma unroll
            for (int r = 0; r < 4; ++r)
                pre[(size_t)(brow + r) * NH + n] = acc[ct][bt][r] + LOINV * acr[ct][bt][r] + bias;
        }
    }
}

// ---------------------------------------------------------------------------
// Normalize + hi/lo split: y = a[j]*relu(pre)+c[j]; 8 elems/thread
__global__ __launch_bounds__(256) void norm_hl(
        const float* __restrict__ pre, const float* __restrict__ a,
        const float* __restrict__ c, _Float16* __restrict__ hi,
        _Float16* __restrict__ lo) {
    int idx = blockIdx.x * 256 + threadIdx.x;   // over B*NH/8
    int j = (idx * 8) % NH;
    float4 v0 = ((const float4*)pre)[idx * 2];
    float4 v1 = ((const float4*)pre)[idx * 2 + 1];
    float y[8] = {
        a[j+0] * fmaxf(v0.x, 0.f) + c[j+0], a[j+1] * fmaxf(v0.y, 0.f) + c[j+1],
        a[j+2] * fmaxf(v0.z, 0.f) + c[j+2], a[j+3] * fmaxf(v0.w, 0.f) + c[j+3],
        a[j+4] * fmaxf(v1.x, 0.f) + c[j+4], a[j+5] * fmaxf(v1.y, 0.f) + c[j+5],
        a[j+6] * fmaxf(v1.z, 0.f) + c[j+6], a[j+7] * fmaxf(v1.w, 0.f) + c[j+7] };
    f16x8 h8, l8;
    #pragma unroll
    for (int jj = 0; jj < 8; ++jj) {
        _Float16 h = (_Float16)y[jj];
        h8[jj] = h;
        l8[jj] = (_Float16)((y[jj] - (float)h) * LOSCALE);
    }
    *(f16x8*)(hi + (size_t)idx * 8) = h8;
    *(f16x8*)(lo + (size_t)idx * 8) = l8;
}

// ---------------------------------------------------------------------------
// Gate GEMM (fp16x3 MFMA): gateT[st][b] = clip(acts[b,:].WgPad[st,:], 0, 1);
// tg[b] (+)= sum_st gate.  grid B/64, block 256; wave: 48 st-rows x 16 b-cols.
__global__ __launch_bounds__(256, 2) void gate_mfma(
        const _Float16* __restrict__ aHi, const _Float16* __restrict__ aLo,
        const _Float16* __restrict__ WgHi, const _Float16* __restrict__ WgLo,
        float* __restrict__ gateT, float* __restrict__ tg, int firstLayer) {
    int tid = threadIdx.x;
    int w = tid >> 6, l = tid & 63, lr = l & 15, lq = l >> 4;
    int b = blockIdx.x * 64 + w * 16 + lr;
    const _Float16* arowH = aHi + (size_t)b * NH;
    const _Float16* arowL = aLo + (size_t)b * NH;
    f32x4 acc[3], acr[3];
    #pragma unroll
    for (int rt = 0; rt < 3; ++rt)
        #pragma unroll
        for (int r = 0; r < 4; ++r) { acc[rt][r] = 0.f; acr[rt][r] = 0.f; }
    #pragma unroll
    for (int kc = 0; kc < 12; ++kc) {
        int k0 = kc * 32 + lq * 8;
        f16x8 bhi = *(const f16x8*)(arowH + k0);
        f16x8 blo = *(const f16x8*)(arowL + k0);
        #pragma unroll
        for (int rt = 0; rt < 3; ++rt) {
            size_t off = (size_t)(rt * 16 + lr) * NH + k0;
            f16x8 ahi = *(const f16x8*)(WgHi + off);
            f16x8 alo = *(const f16x8*)(WgLo + off);
            acc[rt] = __builtin_amdgcn_mfma_f32_16x16x32_f16(ahi, bhi, acc[rt], 0, 0, 0);
            acr[rt] = __builtin_amdgcn_mfma_f32_16x16x32_f16(ahi, blo, acr[rt], 0, 0, 0);
            acr[rt] = __builtin_amdgcn_mfma_f32_16x16x32_f16(alo, bhi, acr[rt], 0, 0, 0);
        }
    }
    float gsum = 0.f;
    #pragma unroll
    for (int rt = 0; rt < 3; ++rt)
        #pragma unroll
        for (int r = 0; r < 4; ++r) {
            int st = rt * 16 + lq * 4 + r;
            if (st < 36) {
                float p = acc[rt][r] + LOINV * acr[rt][r];
                float g = fminf(fmaxf(p, 0.f), 1.f);
                gateT[(size_t)st * BATCH + b] = g;
                gsum += g;
            }
        }
    gsum += __shfl_xor(gsum, 16, 64);
    gsum += __shfl_xor(gsum, 32, 64);
    if (lq == 0) tg[b] = (firstLayer ? 0.f : tg[b]) + gsum;
}

// ---------------------------------------------------------------------------
// Routed layer (fp16x3 MFMA, transposed D^T[e][b]).
// grid (B/64, 2), block 256 (4 waves). Block: 64 batch rows (ct=4), targets
// t0..t0+2 (t0 = blockIdx.y*3). Wave w: e-tile [w*16, w*16+16).
__global__ __launch_bounds__(256, 2) void layer_data_mfma(
        const _Float16* __restrict__ aHi, const _Float16* __restrict__ aLo,
        const float* __restrict__ gateT, const _Float16* __restrict__ Wdhi,
        const _Float16* __restrict__ Wdlo, const float* __restrict__ bd_l,
        float* __restrict__ pre) {
    int tid = threadIdx.x;
    int w = tid >> 6, l = tid & 63, lr = l & 15, lq = l >> 4;
    int b0 = blockIdx.x * 64;
    int t0 = blockIdx.y * 3;
    int e0 = w * 16;
    f32x4 acc[3][4];
    #pragma unroll
    for (int t = 0; t < 3; ++t)
        #pragma unroll
        for (int ct = 0; ct < 4; ++ct)
            #pragma unroll
            for (int r = 0; r < 4; ++r) acc[t][ct][r] = 0.f;
    for (int s = 0; s < 6; ++s) {
        f16x8 bhi[4][2], blo[4][2];   // [ct][ks]
        #pragma unroll
        for (int ct = 0; ct < 4; ++ct) {
            size_t arow = (size_t)(b0 + ct * 16 + lr) * NH + s * 64 + lq * 8;
            #pragma unroll
            for (int ks = 0; ks < 2; ++ks) {
                bhi[ct][ks] = *(const f16x8*)(aHi + arow + ks * 32);
                blo[ct][ks] = *(const f16x8*)(aLo + arow + ks * 32);
            }
        }
        #pragma unroll
        for (int tt = 0; tt < 3; ++tt) {
            int t = t0 + tt;
            float g[4];
            #pragma unroll
            for (int ct = 0; ct < 4; ++ct)
                g[ct] = gateT[(size_t)(s * 6 + t) * BATCH + b0 + ct * 16 + lr];
            size_t wb = ((size_t)(s * 6 + t) * 64 + e0 + lr) * 64 + lq * 8;
            f16x8 ah0 = *(const f16x8*)(Wdhi + wb);
            f16x8 ah1 = *(const f16x8*)(Wdhi + wb + 32);
            f16x8 al0 = *(const f16x8*)(Wdlo + wb);
            f16x8 al1 = *(const f16x8*)(Wdlo + wb + 32);
            float bdv[4];
            #pragma unroll
            for (int r = 0; r < 4; ++r)
                bdv[r] = bd_l[(s * 6 + t) * 64 + e0 + lq * 4 + r];
            #pragma unroll
            for (int ct = 0; ct < 4; ++ct) {
                f32x4 ph, pc;
                #pragma unroll
                for (int r = 0; r < 4; ++r) { ph[r] = 0.f; pc[r] = 0.f; }
                ph = __builtin_amdgcn_mfma_f32_16x16x32_f16(ah0, bhi[ct][0], ph, 0, 0, 0);
                ph = __builtin_amdgcn_mfma_f32_16x16x32_f16(ah1, bhi[ct][1], ph, 0, 0, 0);
                pc = __builtin_amdgcn_mfma_f32_16x16x32_f16(ah0, blo[ct][0], pc, 0, 0, 0);
                pc = __builtin_amdgcn_mfma_f32_16x16x32_f16(ah1, blo[ct][1], pc, 0, 0, 0);
                pc = __builtin_amdgcn_mfma_f32_16x16x32_f16(al0, bhi[ct][0], pc, 0, 0, 0);
                pc = __builtin_amdgcn_mfma_f32_16x16x32_f16(al1, bhi[ct][1], pc, 0, 0, 0);
                #pragma unroll
                for (int r = 0; r < 4; ++r)
                    acc[tt][ct][r] += g[ct] * (ph[r] + LOINV * pc[r] + bdv[r]);
            }
        }
    }
    #pragma unroll
    for (int tt = 0; tt < 3; ++tt)
        #pragma unroll
        for (int ct = 0; ct < 4; ++ct)
            #pragma unroll
            for (int r = 0; r < 4; ++r)
                pre[(size_t)(b0 + ct * 16 + lr) * NH + (t0 + tt) * 64 + e0 + lq * 4 + r]
                    = acc[tt][ct][r];
}

// ---------------------------------------------------------------------------
// Output head GEMM (fp16x3 MFMA) + tg copy.
__global__ __launch_bounds__(256, 2) void out_mfma(
        const _Float16* __restrict__ aHi, const _Float16* __restrict__ aLo,
        const _Float16* __restrict__ OutHi, const _Float16* __restrict__ OutLo,
        const float* __restrict__ tg, float* __restrict__ dout) {
    int tid = threadIdx.x;
    int w = tid >> 6, l = tid & 63, lr = l & 15, lq = l >> 4;
    int b = blockIdx.x * 64 + w * 16 + lr;
    const _Float16* arowH = aHi + (size_t)b * NH;
    const _Float16* arowL = aLo + (size_t)b * NH;
    f32x4 acc, acr;
    #pragma unroll
    for (int r = 0; r < 4; ++r) { acc[r] = 0.f; acr[r] = 0.f; }
    #pragma unroll
    for (int kc = 0; kc < 12; ++kc) {
        int k0 = kc * 32 + lq * 8;
        f16x8 bhi = *(const f16x8*)(arowH + k0);
        f16x8 blo = *(const f16x8*)(arowL + k0);
        size_t off = (size_t)lr * NH + k0;
        f16x8 ahi = *(const f16x8*)(OutHi + off);
        f16x8 alo = *(const f16x8*)(OutLo + off);
        acc = __builtin_amdgcn_mfma_f32_16x16x32_f16(ahi, bhi, acc, 0, 0, 0);
        acr = __builtin_amdgcn_mfma_f32_16x16x32_f16(ahi, blo, acr, 0, 0, 0);
        acr = __builtin_amdgcn_mfma_f32_16x16x32_f16(alo, bhi, acr, 0, 0, 0);
    }
    #pragma unroll
    for (int r = 0; r < 4; ++r) {
        int o = lq * 4 + r;
        if (o < NOUT)
            dout[(size_t)b * NOUT + o] = acc[r] + LOINV * acr[r];
    }
    if (lq == 0) dout[(size_t)BATCH * NOUT + b] = tg[b];
}

// ---------------------------------------------------------------------------
extern "C" void kernel_launch(void* const* d_in, const int* in_sizes, int n_in,
                              void* d_out, int out_size, void* d_ws, size_t ws_size,
                              hipStream_t stream) {
    const float* x        = (const float*)d_in[0];
    const float* gamma_in = (const float*)d_in[1];
    const float* beta_in  = (const float*)d_in[2];
    const float* W_in     = (const float*)d_in[3];
    const float* b_in     = (const float*)d_in[4];
    const float* Wg       = (const float*)d_in[5];
    const float* Wd       = (const float*)d_in[6];
    const float* bd       = (const float*)d_in[7];
    const float* gamma_h  = (const float*)d_in[8];
    const float* beta_h   = (const float*)d_in[9];
    const float* W_out    = (const float*)d_in[10];
    float* dout = (float*)d_out;
    float* ws = (float*)d_ws;

    // workspace layout (float offsets), total ~14.59M floats = 58.4 MiB
    float* psum  = ws;                              // 128*1024
    float* psq   = ws + 131072;                     // 128*1024
    float* avec  = ws + 262144;                     // 1024
    float* cvec  = ws + 263168;                     // 1024
    float* bp    = ws + 264192;                     // 1024
    float* pre   = ws + 265216;                     // B*NH f32
    _Float16* actsHi = (_Float16*)(ws + 6556672);   // B*NH f16
    _Float16* actsLo = (_Float16*)(ws + 9702400);   // B*NH f16
    float* gateT = ws + 12848128;                   // 36*B f32
    float* tg    = ws + 13437952;                   // B
    _Float16* WpHi = (_Float16*)(ws + 13454336);    // 384*784 f16
    _Float16* WpLo = (_Float16*)(ws + 13604864);    // 384*784 f16
    _Float16* WdHiAll = (_Float16*)(ws + 13755392); // 5*36*4096 f16
    _Float16* WdLoAll = (_Float16*)(ws + 14124032); // 5*36*4096 f16
    _Float16* WgHiAll = (_Float16*)(ws + 14492672); // 5*48*384 f16
    _Float16* WgLoAll = (_Float16*)(ws + 14538752); // 5*48*384 f16
    _Float16* OutHi   = (_Float16*)(ws + 14584832); // 16*384 f16
    _Float16* OutLo   = (_Float16*)(ws + 14587904); // 16*384 f16

    dim3 blk(256);

    // ---- prep: input BN fold + all weight split-casts (up front)
    stats_partial<<<dim3(4, NPART), blk, 0, stream>>>(x, NIN, 0, psum, psq);
    stats_finalize<<<dim3(4), blk, 0, stream>>>(psum, psq, NIN, gamma_in, beta_in, avec, cvec);
    scale_win_hl<<<dim3((NH * NIN / 4 + 255) / 256), blk, 0, stream>>>(W_in, avec, WpHi, WpLo);
    bias_in<<<dim3(NH), dim3(64), 0, stream>>>(W_in, b_in, cvec, bp);
    conv_hl<<<dim3((5 * 36 * 4096 / 4 + 255) / 256), blk, 0, stream>>>(
            Wd, WdHiAll, WdLoAll, 5 * 36 * 4096 / 4);
    prep_wg<<<dim3((5 * 48 * 384 + 255) / 256), blk, 0, stream>>>(Wg, WgHiAll, WgLoAll);
    prep_wout<<<dim3((16 * 384 + 255) / 256), blk, 0, stream>>>(W_out, OutHi, OutLo);

    // ---- input GEMM (fp16x3 MFMA) -> pre f32
    gemm_in_mfma<<<dim3(BATCH / 128, 4), blk, 0, stream>>>(x, WpHi, WpLo, bp, pre);

    // ---- hidden layers
    for (int j = 0; j < NLAYERS; ++j) {
        stats_partial<<<dim3(2, NPART), blk, 0, stream>>>(pre, NH, 1, psum, psq);
        stats_finalize<<<dim3(2), blk, 0, stream>>>(psum, psq, NH,
                gamma_h + j * NH, beta_h + j * NH, avec, cvec);
        norm_hl<<<dim3(BATCH * NH / 8 / 256), blk, 0, stream>>>(pre, avec, cvec, actsHi, actsLo);
        if (j < NLAYERS - 1) {
            int l = j;
            gate_mfma<<<dim3(BATCH / 64), blk, 0, stream>>>(
                    actsHi, actsLo, WgHiAll + (size_t)l * 48 * 384,
                    WgLoAll + (size_t)l * 48 * 384, gateT, tg, l == 0);
            layer_data_mfma<<<dim3(BATCH / 64, 2), blk, 0, stream>>>(
                    actsHi, actsLo, gateT, WdHiAll + (size_t)l * 36 * 4096,
                    WdLoAll + (size_t)l * 36 * 4096, bd + (size_t)l * 36 * 64, pre);
        }
    }

    // ---- output head + total_gate
    out_mfma<<<dim3(BATCH / 64), blk, 0, stream>>>(actsHi, actsLo, OutHi, OutLo, tg, dout);
}